// Round 12
// baseline (128.031 us; speedup 1.0000x reference)
//
#include <hip/hip_runtime.h>
#include <hip/hip_bf16.h>

typedef __bf16 bf16x8 __attribute__((ext_vector_type(8)));
typedef float f32x4 __attribute__((ext_vector_type(4)));
typedef unsigned short u16x8 __attribute__((ext_vector_type(8)));

#define GN    1024
#define BATCH 64
#define CIN   256
#define COUT  256
#define NG    4                      // one 16B g-quad per block
#define A_ELEMS (BATCH * CIN)        // per-tile: 16384 ushorts = 32 KB
#define WSLICE  4096                 // 32 o-rows x 32 k x 4B

#define G_AS __attribute__((address_space(1)))
#define L_AS __attribute__((address_space(3)))

static __device__ __forceinline__ void gload16(const void* g, void* l) {
  __builtin_amdgcn_global_load_lds((const G_AS void*)g, (L_AS void*)l, 16, 0, 0);
}

static __device__ __forceinline__ void vmwait(int n) {
  if (n == 0)       asm volatile("s_waitcnt vmcnt(0)"  ::: "memory");
  else if (n == 4)  asm volatile("s_waitcnt vmcnt(4)"  ::: "memory");
  else if (n == 20) asm volatile("s_waitcnt vmcnt(20)" ::: "memory");
}

static __device__ __forceinline__ ushort f2bf(float f) {
  __hip_bfloat16 h = __float2bfloat16(f);
  return *reinterpret_cast<ushort*>(&h);
}
static __device__ __forceinline__ float bf2f(ushort u) {
  uint v = (uint)u << 16;
  return *reinterpret_cast<float*>(&v);
}

// ---------------------------------------------------------------------------
// FUSED kernel: reads x DIRECTLY (no k1, no xT intermediate).
// 256 blocks (1/CU, 160 KB LDS), block owns g-quad [4q, 4q+4).
// XCD swizzle q=(bid&7)*32+(bid>>3): the 4 sibling blocks sharing each 64B
// x-line land on the same XCD-L2 concurrently; x (67 MB) also fits L3.
// Prologue: A-quad reg-staged (float4 = 4 g's per (b,i), fully consumed),
// cvt->bf16, XOR-swizzled ds_write into 4 x 32KB tiles; ONE barrier total.
// K-loop: W streamed in 4KB o-half slices, per-wave 2-buf, counted vmcnt
// (steady 4; 20,20 after each epilogue's 16 stores; 0 at the end).
// Epilogue: outT[g][o][b] bf16, 16 ushort4 stores per thread per g.
// ---------------------------------------------------------------------------
__global__ __launch_bounds__(256, 1) void k_fused_gemm(
    const float* __restrict__ x, const float* __restrict__ W,
    const float* __restrict__ bias, float* __restrict__ out,
    ushort* __restrict__ outT, int use_ws)
{
  __shared__ __align__(16) unsigned char lds[4 * A_ELEMS * 2 + 4 * 2 * WSLICE]; // 160 KB
  ushort* lA        = (ushort*)lds;            // 4 tiles [b][i-swizzled]
  unsigned char* lW = lds + 4 * A_ELEMS * 2;

  const int tid  = threadIdx.x;
  const int wave = tid >> 6;
  const int lane = tid & 63;

  const int bid    = blockIdx.x;
  const int q      = (bid & 7) * 32 + (bid >> 3);  // XCD-grouped quad id
  const int g_base = q * 4;

  const int arow = lane & 15;
  const int qq   = lane >> 4;
  const int oc   = 64 * wave + arow;

  unsigned char* lWw = lW + wave * (2 * WSLICE);
  const int swz  = ((lane & 7) ^ ((lane >> 3) & 7)) << 4;
  const int wrow = lane >> 3;

  // stage one 4KB W slice: g, o-half oh (32 rows), k-window ks
  auto stage_w = [&](int gg, int oh, int ks, int buf) {
    unsigned char* ldb = lWw + buf * WSLICE;
    const unsigned char* gb =
        (const unsigned char*)(W + ((size_t)gg * COUT + 64 * wave + 32 * oh) * CIN)
        + ks * 128 + swz;
#pragma unroll
    for (int j = 0; j < 4; ++j)
      gload16(gb + (size_t)(8 * j + wrow) * (CIN * 4), ldb + j * 1024);
  };

  // ---- bias preload (16 loads, retired by the barrier) ----
  float bvv[NG][4];
#pragma unroll
  for (int gi = 0; gi < NG; ++gi)
#pragma unroll
    for (int n = 0; n < 4; ++n)
      bvv[gi][n] = bias[(g_base + gi) * COUT + oc + n * 16];

  // ---- W prefetch: slices s=0 (oh0,ks0)->buf0, s=1 (oh0,ks1)->buf1 ----
  stage_w(g_base, 0, 0, 0);
  stage_w(g_base, 0, 1, 1);
  __builtin_amdgcn_sched_barrier(0);

  // ---- A-quad reg-staged from x: wave w owns b-rows [16w,16w+16) ----
  {
    const int bl = 16 * wave + 2 * ((lane >> 3) & 7);
#pragma unroll
    for (int bb = 0; bb < 2; ++bb) {
      const int b = bl + bb;
      const int bswz = (b & 7);  // chunk-slot XOR key
#pragma unroll
      for (int jj = 0; jj < 4; ++jj) {
        const int c = (lane & 7) + 8 * jj;   // content chunk (i/8)
        float4 v[8];
#pragma unroll
        for (int k = 0; k < 8; ++k)
          v[k] = *reinterpret_cast<const float4*>(
              &x[((size_t)b * CIN + 8 * c + k) * GN + g_base]);
        u16x8 u0, u1, u2, u3;
#pragma unroll
        for (int k = 0; k < 8; ++k) {
          u0[k] = f2bf(v[k].x);
          u1[k] = f2bf(v[k].y);
          u2[k] = f2bf(v[k].z);
          u3[k] = f2bf(v[k].w);
        }
        const int slot = (c ^ bswz) * 8;     // element offset in row
        ushort* r0 = lA + 0 * A_ELEMS + b * CIN + slot;
        ushort* r1 = lA + 1 * A_ELEMS + b * CIN + slot;
        ushort* r2 = lA + 2 * A_ELEMS + b * CIN + slot;
        ushort* r3 = lA + 3 * A_ELEMS + b * CIN + slot;
        *reinterpret_cast<u16x8*>(r0) = u0;
        *reinterpret_cast<u16x8*>(r1) = u1;
        *reinterpret_cast<u16x8*>(r2) = u2;
        *reinterpret_cast<u16x8*>(r3) = u3;
      }
    }
  }
  __syncthreads();   // full drain: A visible, W slices 0,1 ready

#pragma unroll
  for (int gi = 0; gi < NG; ++gi) {
    const int g = g_base + gi;
    const ushort* lAg = lA + gi * A_ELEMS;

    f32x4 acc[4][4];
#pragma unroll
    for (int m = 0; m < 4; ++m)
#pragma unroll
      for (int n = 0; n < 4; ++n)
        acc[m][n] = {0.f, 0.f, 0.f, 0.f};

#pragma unroll
    for (int oh = 0; oh < 2; ++oh) {
#pragma unroll
      for (int ks = 0; ks < 8; ++ks) {
        const int s = gi * 16 + oh * 8 + ks;
        // vmcnt: steady 4; first two steps after an epilogue leave the 16
        // stores + next slice outstanding (20); final step drains.
        if (s == 63)                       vmwait(0);
        else if (gi > 0 && (s & 15) < 2)   vmwait(20);
        else                               vmwait(4);
        __builtin_amdgcn_sched_barrier(0);

        unsigned char* wb = lWw + (s & 1) * WSLICE;
        const int key = (arow & 7) << 4;

        float4 f[2][2];
#pragma unroll
        for (int n2 = 0; n2 < 2; ++n2) {
          int r = n2 * 16 + arow;
          f[n2][0] = *reinterpret_cast<const float4*>(wb + r * 128 + ((qq * 32) ^ key));
          f[n2][1] = *reinterpret_cast<const float4*>(wb + r * 128 + ((qq * 32 + 16) ^ key));
        }
        bf16x8 afr[4];
        const int i0 = ks * 32 + qq * 8;
#pragma unroll
        for (int m = 0; m < 4; ++m) {
          int row = m * 16 + arow;
          afr[m] = *reinterpret_cast<const bf16x8*>(
              &lAg[row * CIN + (i0 ^ ((row & 7) << 3))]);
        }

        asm volatile("s_waitcnt lgkmcnt(0)" ::: "memory");
        __builtin_amdgcn_sched_barrier(0);
        if (s + 2 < 64) {
          const int s2 = s + 2;
          stage_w(g_base + (s2 >> 4), (s2 >> 3) & 1, s2 & 7, s2 & 1);
        }
        __builtin_amdgcn_sched_barrier(0);

        bf16x8 bfr[2];
#pragma unroll
        for (int n2 = 0; n2 < 2; ++n2) {
          bfr[n2][0] = (__bf16)f[n2][0].x; bfr[n2][1] = (__bf16)f[n2][0].y;
          bfr[n2][2] = (__bf16)f[n2][0].z; bfr[n2][3] = (__bf16)f[n2][0].w;
          bfr[n2][4] = (__bf16)f[n2][1].x; bfr[n2][5] = (__bf16)f[n2][1].y;
          bfr[n2][6] = (__bf16)f[n2][1].z; bfr[n2][7] = (__bf16)f[n2][1].w;
        }

        __builtin_amdgcn_s_setprio(1);
#pragma unroll
        for (int m = 0; m < 4; ++m)
#pragma unroll
          for (int n2 = 0; n2 < 2; ++n2)
            acc[m][2 * oh + n2] = __builtin_amdgcn_mfma_f32_16x16x32_bf16(
                afr[m], bfr[n2], acc[m][2 * oh + n2], 0, 0, 0);
        __builtin_amdgcn_s_setprio(0);
      }
    }

    // ---- epilogue for g: 16 ushort4 stores to outT[g][o][b] ----
    if (use_ws) {
#pragma unroll
      for (int m = 0; m < 4; ++m) {
#pragma unroll
        for (int n = 0; n < 4; ++n) {
          int o = oc + n * 16;
          ushort4 u;
          u.x = f2bf(acc[m][n][0] + bvv[gi][n]);
          u.y = f2bf(acc[m][n][1] + bvv[gi][n]);
          u.z = f2bf(acc[m][n][2] + bvv[gi][n]);
          u.w = f2bf(acc[m][n][3] + bvv[gi][n]);
          *reinterpret_cast<ushort4*>(
              &outT[((size_t)g * COUT + o) * BATCH + m * 16 + 4 * qq]) = u;
        }
      }
    } else {
#pragma unroll
      for (int m = 0; m < 4; ++m) {
#pragma unroll
        for (int n = 0; n < 4; ++n) {
          int o = oc + n * 16;
#pragma unroll
          for (int j = 0; j < 4; ++j) {
            int b = m * 16 + 4 * qq + j;
            out[((size_t)b * COUT + o) * GN + g] = acc[m][n][j] + bvv[gi][n];
          }
        }
      }
    }
    __builtin_amdgcn_sched_barrier(0);
  }
}

// ---------------------------------------------------------------------------
// Kernel 3: transpose  outT[g][o][b] (bf16) -> out[b][o][g] (f32)
// (R7 structure, verified there.) block = 64-g tile x one o.
// ---------------------------------------------------------------------------
__global__ __launch_bounds__(256) void k_transpose_out(
    const ushort* __restrict__ outT, float* __restrict__ out)
{
  __shared__ float tile[64][65];  // [g][b]
  const int g0 = blockIdx.x * 64;
  const int o  = blockIdx.y;
  const int t  = threadIdx.x;

  {
    const int a = t & 7;
#pragma unroll
    for (int p = 0; p < 2; ++p) {
      int gl = p * 32 + (t >> 3);
      int4 raw = *reinterpret_cast<const int4*>(
          &outT[((size_t)(g0 + gl) * COUT + o) * BATCH + a * 8]);
      const ushort* us = reinterpret_cast<const ushort*>(&raw);
#pragma unroll
      for (int e = 0; e < 8; ++e) tile[gl][a * 8 + e] = bf2f(us[e]);
    }
  }
  __syncthreads();

  {
    const int a2 = t & 15;
#pragma unroll
    for (int p = 0; p < 4; ++p) {
      int bl = p * 16 + (t >> 4);
      float4 v;
      v.x = tile[4 * a2 + 0][bl];
      v.y = tile[4 * a2 + 1][bl];
      v.z = tile[4 * a2 + 2][bl];
      v.w = tile[4 * a2 + 3][bl];
      *reinterpret_cast<float4*>(
          &out[((size_t)bl * COUT + o) * GN + g0 + 4 * a2]) = v;
    }
  }
}

// ---------------------------------------------------------------------------
extern "C" void kernel_launch(void* const* d_in, const int* in_sizes, int n_in,
                              void* d_out, int out_size, void* d_ws, size_t ws_size,
                              hipStream_t stream) {
  const float* x  = (const float*)d_in[0];
  const float* W  = (const float*)d_in[1];
  const float* bs = (const float*)d_in[2];
  float* out      = (float*)d_out;

  const size_t oT_elems = (size_t)GN * COUT * BATCH;  // 33.5 MB
  const bool use_ws = ws_size >= oT_elems * sizeof(ushort);

  ushort* outT = (ushort*)d_ws;

  k_fused_gemm<<<GN / NG, 256, 0, stream>>>(x, W, bs, out,
                                            use_ws ? outT : nullptr,
                                            use_ws ? 1 : 0);
  if (use_ws) {
    dim3 grid3(GN / 64, COUT);
    k_transpose_out<<<grid3, 256, 0, stream>>>(outT, out);
  }
}